// Round 2
// baseline (1190.382 us; speedup 1.0000x reference)
//
#include <hip/hip_runtime.h>
#include <cstdint>
#include <cstddef>

// GraphResBlock2 on MI355X — CSR-fused segment-mean GEMMs, bf16 MFMA.
// N=100000, E=700000, C1=128, C2=256, 7 edge types.
// Workspace ~114 MB: CSR (off/cnt/pcol/inv ~11.2MB) + Bt transposes (1.5MB)
// + x1 bf16 (51.2MB) + convb bf16 (51.2MB) + stats. scp lives in d_out (f32).

#define N_ET 7

typedef __bf16 bf16;
typedef __bf16 bf16x8 __attribute__((ext_vector_type(8)));
typedef __bf16 bf16x4 __attribute__((ext_vector_type(4)));
typedef float f32x4v __attribute__((ext_vector_type(4)));

// ---------------- CSR build ----------------

__global__ void count_edges_k(const int* __restrict__ row, const int* __restrict__ et,
                              int* __restrict__ cnt, int E) {
  int e = blockIdx.x * 256 + threadIdx.x;
  if (e < E) atomicAdd(&cnt[row[e] * N_ET + et[e]], 1);
}

__global__ void inv_counts_k(const int* __restrict__ cnt, float* __restrict__ inv, int n) {
  int i = blockIdx.x * 256 + threadIdx.x;
  if (i < n) inv[i] = 1.0f / fmaxf((float)cnt[i], 1.0f);
}

__global__ __launch_bounds__(1024) void scan1_k(const int* __restrict__ cnt,
                                                int* __restrict__ off,
                                                int* __restrict__ bsum, int n) {
  __shared__ int s[1024];
  int tid = threadIdx.x;
  int i = blockIdx.x * 1024 + tid;
  int v = (i < n) ? cnt[i] : 0;
  s[tid] = v;
  __syncthreads();
  for (int d = 1; d < 1024; d <<= 1) {
    int t = (tid >= d) ? s[tid - d] : 0;
    __syncthreads();
    s[tid] += t;
    __syncthreads();
  }
  if (i < n) off[i] = s[tid] - v;            // exclusive within block
  if (tid == 1023) bsum[blockIdx.x] = s[1023];
}

__global__ __launch_bounds__(1024) void scan2_k(int* __restrict__ bsum, int nb) {
  __shared__ int s[1024];
  int tid = threadIdx.x;
  int v = (tid < nb) ? bsum[tid] : 0;
  s[tid] = v;
  __syncthreads();
  for (int d = 1; d < 1024; d <<= 1) {
    int t = (tid >= d) ? s[tid - d] : 0;
    __syncthreads();
    s[tid] += t;
    __syncthreads();
  }
  if (tid < nb) bsum[tid] = s[tid] - v;      // exclusive
}

__global__ __launch_bounds__(1024) void scan3_k(int* __restrict__ off,
                                                const int* __restrict__ bsum,
                                                int n, int total) {
  int i = blockIdx.x * 1024 + threadIdx.x;
  if (i < n) off[i] += bsum[blockIdx.x];
  if (i == 0) off[n] = total;
}

__global__ void place_k(const int* __restrict__ row, const int* __restrict__ col,
                        const int* __restrict__ et, const int* __restrict__ off,
                        int* __restrict__ cur, int* __restrict__ pcol, int E) {
  int e = blockIdx.x * 256 + threadIdx.x;
  if (e >= E) return;
  int seg = row[e] * N_ET + et[e];
  int pos = off[seg] + atomicAdd(&cur[seg], 1);
  pcol[pos] = col[e];
}

// ---------------- weight transpose (f32 [K,256] -> bf16 [256,K]) ----------------

__global__ void transpose_w_k(const float* __restrict__ W, bf16* __restrict__ Bt, int K) {
  int i = blockIdx.x * 256 + threadIdx.x;
  if (i < K * 256) {
    int k = i >> 8, n = i & 255;
    Bt[(size_t)n * K + k] = (bf16)W[i];
  }
}

// ---------------- fused aggregate + GEMM ----------------
// Cout[M,256] = Aeff[M,K] @ W[K,256]
//   AGG:  Aeff[m, t*CF+c] = inv[m*7+t] * sum_{p in seg(m,t)} X[pcol[p], c]
//   !AGG: Aeff = X (f32 row-major [M,K])
// Tile: 128 rows x 256 cols, 4 waves (2x2: 64 rows x 128 cols each), BK=32.
template <int CF, bool AGG, typename XT, typename OT>
__launch_bounds__(256, 2)
__global__ void agg_gemm_k(const XT* __restrict__ X, const bf16* __restrict__ Bt,
                           const int* __restrict__ off, const int* __restrict__ pcol,
                           const float* __restrict__ inv, OT* __restrict__ Cout,
                           int M, int K) {
  __shared__ alignas(16) bf16 As[128][40];
  __shared__ alignas(16) bf16 Bs[256][40];
  const int t = threadIdx.x;
  const int m0 = blockIdx.x * 128;
  const int lane = t & 63, w = t >> 6;
  const int wm = (w >> 1) * 64;
  const int wn = (w & 1) * 128;
  const int l15 = lane & 15, quad = lane >> 4;

  f32x4v acc[4][8];
#pragma unroll
  for (int i = 0; i < 4; ++i)
#pragma unroll
    for (int j = 0; j < 8; ++j) acc[i][j] = (f32x4v){0.f, 0.f, 0.f, 0.f};

  const int r = t >> 1, h = t & 1;
  const int m = m0 + r;
  const bool mv = (m < M);

  for (int k0 = 0; k0 < K; k0 += 32) {
    // ---- A staging ----
    if constexpr (AGG) {
      const int tt = k0 / CF;
      const int cb = (k0 % CF) + h * 16;
      int sS = 0, sE = 0;
      float sc = 0.f;
      if (mv) {
        int seg = m * N_ET + tt;
        sS = off[seg];
        sE = off[seg + 1];
        sc = inv[seg];
      }
      float s[16];
#pragma unroll
      for (int j = 0; j < 16; ++j) s[j] = 0.f;
      for (int p = sS; p < sE; ++p) {
        int cI = pcol[p];
        if constexpr (CF == 128) {
          const float* xp = (const float*)X + (size_t)cI * CF + cb;
          float4 v0 = *(const float4*)(xp + 0);
          float4 v1 = *(const float4*)(xp + 4);
          float4 v2 = *(const float4*)(xp + 8);
          float4 v3 = *(const float4*)(xp + 12);
          s[0] += v0.x; s[1] += v0.y; s[2] += v0.z; s[3] += v0.w;
          s[4] += v1.x; s[5] += v1.y; s[6] += v1.z; s[7] += v1.w;
          s[8] += v2.x; s[9] += v2.y; s[10] += v2.z; s[11] += v2.w;
          s[12] += v3.x; s[13] += v3.y; s[14] += v3.z; s[15] += v3.w;
        } else {
          const bf16* xp = (const bf16*)X + (size_t)cI * CF + cb;
          bf16x8 v0 = *(const bf16x8*)(xp);
          bf16x8 v1 = *(const bf16x8*)(xp + 8);
#pragma unroll
          for (int j = 0; j < 8; ++j) { s[j] += (float)v0[j]; s[8 + j] += (float)v1[j]; }
        }
      }
      bf16x8 o0, o1;
#pragma unroll
      for (int j = 0; j < 8; ++j) {
        o0[j] = (bf16)(s[j] * sc);
        o1[j] = (bf16)(s[8 + j] * sc);
      }
      *(bf16x8*)&As[r][h * 16] = o0;
      *(bf16x8*)&As[r][h * 16 + 8] = o1;
    } else {
      const float* xp = (const float*)X + (size_t)m * K + k0 + h * 16;
      float4 v0, v1, v2, v3;
      if (mv) {
        v0 = *(const float4*)(xp + 0);
        v1 = *(const float4*)(xp + 4);
        v2 = *(const float4*)(xp + 8);
        v3 = *(const float4*)(xp + 12);
      } else {
        v0 = v1 = v2 = v3 = make_float4(0.f, 0.f, 0.f, 0.f);
      }
      bf16x8 o0, o1;
      o0[0] = (bf16)v0.x; o0[1] = (bf16)v0.y; o0[2] = (bf16)v0.z; o0[3] = (bf16)v0.w;
      o0[4] = (bf16)v1.x; o0[5] = (bf16)v1.y; o0[6] = (bf16)v1.z; o0[7] = (bf16)v1.w;
      o1[0] = (bf16)v2.x; o1[1] = (bf16)v2.y; o1[2] = (bf16)v2.z; o1[3] = (bf16)v2.w;
      o1[4] = (bf16)v3.x; o1[5] = (bf16)v3.y; o1[6] = (bf16)v3.z; o1[7] = (bf16)v3.w;
      *(bf16x8*)&As[r][h * 16] = o0;
      *(bf16x8*)&As[r][h * 16 + 8] = o1;
    }
    // ---- B staging: thread t -> output column nn=t, 32 k's via 4x b128 ----
    {
      const bf16* bp = Bt + (size_t)t * K + k0;
      bf16x8 b0 = *(const bf16x8*)(bp + 0);
      bf16x8 b1 = *(const bf16x8*)(bp + 8);
      bf16x8 b2 = *(const bf16x8*)(bp + 16);
      bf16x8 b3 = *(const bf16x8*)(bp + 24);
      *(bf16x8*)&Bs[t][0] = b0;
      *(bf16x8*)&Bs[t][8] = b1;
      *(bf16x8*)&Bs[t][16] = b2;
      *(bf16x8*)&Bs[t][24] = b3;
    }
    __syncthreads();
    bf16x8 af[4], bfr[8];
#pragma unroll
    for (int f = 0; f < 4; ++f) af[f] = *(const bf16x8*)&As[wm + f * 16 + l15][quad * 8];
#pragma unroll
    for (int g = 0; g < 8; ++g) bfr[g] = *(const bf16x8*)&Bs[wn + g * 16 + l15][quad * 8];
#pragma unroll
    for (int fi = 0; fi < 4; ++fi)
#pragma unroll
      for (int fj = 0; fj < 8; ++fj)
        acc[fi][fj] = __builtin_amdgcn_mfma_f32_16x16x32_bf16(af[fi], bfr[fj], acc[fi][fj], 0, 0, 0);
    __syncthreads();
  }

#pragma unroll
  for (int fi = 0; fi < 4; ++fi) {
    int rbase = m0 + wm + fi * 16 + quad * 4;
#pragma unroll
    for (int rr = 0; rr < 4; ++rr) {
      int rowg = rbase + rr;
      if (rowg < M) {
#pragma unroll
        for (int fj = 0; fj < 8; ++fj)
          Cout[(size_t)rowg * 256 + wn + fj * 16 + l15] = (OT)acc[fi][fj][rr];
      }
    }
  }
}

// ---------------- BN stats / params / elementwise ----------------

__global__ void colstats_bf16_k(const bf16* __restrict__ v, int N,
                                float* __restrict__ s, float* __restrict__ q) {
  int c = threadIdx.x;
  float a = 0.f, b = 0.f;
  for (int r = blockIdx.x; r < N; r += gridDim.x) {
    float x = (float)v[(size_t)r * 256 + c];
    a += x;
    b += x * x;
  }
  unsafeAtomicAdd(&s[c], a);
  unsafeAtomicAdd(&q[c], b);
}

__global__ void colstats_f32_k(const float* __restrict__ v, int N,
                               float* __restrict__ s, float* __restrict__ q) {
  int c = threadIdx.x;
  float a = 0.f, b = 0.f;
  for (int r = blockIdx.x; r < N; r += gridDim.x) {
    float x = v[(size_t)r * 256 + c];
    a += x;
    b += x * x;
  }
  unsafeAtomicAdd(&s[c], a);
  unsafeAtomicAdd(&q[c], b);
}

__global__ void bn_params_k(const float* __restrict__ s, const float* __restrict__ q,
                            const float* __restrict__ g, const float* __restrict__ b,
                            float* __restrict__ scale, float* __restrict__ shift, float invN) {
  int c = threadIdx.x;
  float m = s[c] * invN;
  float var = fmaxf(q[c] * invN - m * m, 0.f);
  float sc = g[c] * rsqrtf(var + 1e-5f);
  scale[c] = sc;
  shift[c] = b[c] - m * sc;
}

// in-place BN+ReLU on bf16 [N,256]
__global__ void bn_relu_ip_k(bf16* __restrict__ v, const float* __restrict__ scale,
                             const float* __restrict__ shift, int total8) {
  int i = blockIdx.x * 256 + threadIdx.x;
  if (i >= total8) return;
  size_t base = (size_t)i * 8;
  int c = (int)(base & 255);
  bf16x8 x = *(const bf16x8*)(v + base);
#pragma unroll
  for (int j = 0; j < 8; ++j)
    x[j] = (bf16)fmaxf((float)x[j] * scale[c + j] + shift[c + j], 0.f);
  *(bf16x8*)(v + base) = x;
}

// out = relu(bnB(convb) + bnS(scp)) ; scp lives in d_out (in-place)
__global__ void final_out_k(const bf16* __restrict__ cb,
                            const float* __restrict__ scB, const float* __restrict__ shB,
                            const float* __restrict__ scS, const float* __restrict__ shS,
                            float* __restrict__ out, int total4) {
  int i = blockIdx.x * 256 + threadIdx.x;
  if (i >= total4) return;
  size_t base = (size_t)i * 4;
  int c = (int)(base & 255);
  bf16x4 vb = *(const bf16x4*)(cb + base);
  float4 vs = *(const float4*)(out + base);
  float4 r;
  r.x = fmaxf((float)vb[0] * scB[c + 0] + shB[c + 0] + vs.x * scS[c + 0] + shS[c + 0], 0.f);
  r.y = fmaxf((float)vb[1] * scB[c + 1] + shB[c + 1] + vs.y * scS[c + 1] + shS[c + 1], 0.f);
  r.z = fmaxf((float)vb[2] * scB[c + 2] + shB[c + 2] + vs.z * scS[c + 2] + shS[c + 2], 0.f);
  r.w = fmaxf((float)vb[3] * scB[c + 3] + shB[c + 3] + vs.w * scS[c + 3] + shS[c + 3], 0.f);
  *(float4*)(out + base) = r;
}

__global__ void sentinel_k(float* __restrict__ out, int n) {
  int i = blockIdx.x * 256 + threadIdx.x;
  if (i < n) out[i] = 12345.0f;
}

// ---------------- launch ----------------

extern "C" void kernel_launch(void* const* d_in, const int* in_sizes, int n_in,
                              void* d_out, int out_size, void* d_ws, size_t ws_size,
                              hipStream_t stream) {
  const float* x  = (const float*)d_in[0];
  const int* ei   = (const int*)d_in[1];
  const int* etp  = (const int*)d_in[2];
  const float* Wa = (const float*)d_in[4];
  const float* ga = (const float*)d_in[5];
  const float* ba = (const float*)d_in[6];
  const float* Wb = (const float*)d_in[7];
  const float* gb = (const float*)d_in[8];
  const float* bb = (const float*)d_in[9];
  const float* W1 = (const float*)d_in[10];
  const float* g1 = (const float*)d_in[11];
  const float* b1 = (const float*)d_in[12];

  const int C1 = 128, C2 = 256;
  const int N = in_sizes[0] / C1;   // 100000
  const int E = in_sizes[2];        // 700000
  const int* row = ei;
  const int* col = ei + E;
  const int NS = N * N_ET;
  const int KA = N_ET * C1;         // 896
  const int KB = N_ET * C2;         // 1792

  // workspace layout (16B aligned)
  size_t need = 0;
  auto alloc = [&](size_t bytes) { size_t o = need; need += (bytes + 15) & ~(size_t)15; return o; };
  char* w = (char*)d_ws;
  int*   off_p = (int*)(w + alloc(((size_t)NS + 1) * 4));
  int*   cnt_p = (int*)(w + alloc((size_t)NS * 4));
  int*   pcol  = (int*)(w + alloc((size_t)E * 4));
  float* inv_p = (float*)(w + alloc((size_t)NS * 4));
  int*   bsum  = (int*)(w + alloc(1024 * 4));
  bf16*  BtA   = (bf16*)(w + alloc((size_t)256 * KA * 2));
  bf16*  BtB   = (bf16*)(w + alloc((size_t)256 * KB * 2));
  bf16*  Bt1   = (bf16*)(w + alloc((size_t)256 * C1 * 2));
  bf16*  x1    = (bf16*)(w + alloc((size_t)N * C2 * 2));
  bf16*  convb = (bf16*)(w + alloc((size_t)N * C2 * 2));
  float* st    = (float*)(w + alloc(12 * 256 * 4));

  if (ws_size < need) {
    sentinel_k<<<(out_size + 255) / 256, 256, 0, stream>>>((float*)d_out, out_size);
    return;
  }

  float* sum_a = st + 0 * 256, *ssq_a = st + 1 * 256;
  float* sum_b = st + 2 * 256, *ssq_b = st + 3 * 256;
  float* sum_s = st + 4 * 256, *ssq_s = st + 5 * 256;
  float* scA = st + 6 * 256, *shA = st + 7 * 256;
  float* scB = st + 8 * 256, *shB = st + 9 * 256;
  float* scS = st + 10 * 256, *shS = st + 11 * 256;

  const float invN = 1.0f / (float)N;
  const int nscan = (NS + 1023) / 1024;
  const int gemm_grid = (N + 127) / 128;
  const int total8 = N * C2 / 8;
  const int total4 = N * C2 / 4;

  // --- CSR build ---
  hipMemsetAsync(cnt_p, 0, (size_t)NS * 4, stream);
  hipMemsetAsync(st, 0, 12 * 256 * 4, stream);
  count_edges_k<<<(E + 255) / 256, 256, 0, stream>>>(row, etp, cnt_p, E);
  inv_counts_k<<<(NS + 255) / 256, 256, 0, stream>>>(cnt_p, inv_p, NS);
  scan1_k<<<nscan, 1024, 0, stream>>>(cnt_p, off_p, bsum, NS);
  scan2_k<<<1, 1024, 0, stream>>>(bsum, nscan);
  scan3_k<<<nscan, 1024, 0, stream>>>(off_p, bsum, NS, E);
  hipMemsetAsync(cnt_p, 0, (size_t)NS * 4, stream);
  place_k<<<(E + 255) / 256, 256, 0, stream>>>(row, col, etp, off_p, cnt_p, pcol, E);

  // --- weight transposes ---
  transpose_w_k<<<(KA * 256 + 255) / 256, 256, 0, stream>>>(Wa, BtA, KA);
  transpose_w_k<<<(KB * 256 + 255) / 256, 256, 0, stream>>>(Wb, BtB, KB);
  transpose_w_k<<<(C1 * 256 + 255) / 256, 256, 0, stream>>>(W1, Bt1, C1);

  // --- conv_a: fused aggregate-GEMM -> conva (bf16, stored in x1 buffer) ---
  agg_gemm_k<128, true, float, bf16><<<gemm_grid, 256, 0, stream>>>(
      x, BtA, off_p, pcol, inv_p, x1, N, KA);
  colstats_bf16_k<<<512, 256, 0, stream>>>(x1, N, sum_a, ssq_a);
  bn_params_k<<<1, 256, 0, stream>>>(sum_a, ssq_a, ga, ba, scA, shA, invN);
  bn_relu_ip_k<<<(total8 + 255) / 256, 256, 0, stream>>>(x1, scA, shA, total8);

  // --- shortcut: x @ W1 -> scp (f32, in d_out) ---
  agg_gemm_k<128, false, float, float><<<gemm_grid, 256, 0, stream>>>(
      x, Bt1, nullptr, nullptr, nullptr, (float*)d_out, N, C1);
  colstats_f32_k<<<512, 256, 0, stream>>>((const float*)d_out, N, sum_s, ssq_s);
  bn_params_k<<<1, 256, 0, stream>>>(sum_s, ssq_s, g1, b1, scS, shS, invN);

  // --- conv_b: fused aggregate-GEMM from x1 -> convb (bf16) ---
  agg_gemm_k<256, true, bf16, bf16><<<gemm_grid, 256, 0, stream>>>(
      x1, BtB, off_p, pcol, inv_p, convb, N, KB);
  colstats_bf16_k<<<512, 256, 0, stream>>>(convb, N, sum_b, ssq_b);
  bn_params_k<<<1, 256, 0, stream>>>(sum_b, ssq_b, gb, bb, scB, shB, invN);

  // --- out = relu(bn(convb) + bn(scp)) ---
  final_out_k<<<(total4 + 255) / 256, 256, 0, stream>>>(
      convb, scB, shB, scS, shS, (float*)d_out, total4);
}

// Round 3
// 1187.111 us; speedup vs baseline: 1.0028x; 1.0028x over previous
//
#include <hip/hip_runtime.h>
#include <cstdint>
#include <cstddef>

// GraphResBlock2 on MI355X — round 3: decoupled aggregation (wave-per-segment,
// materialized bf16 mean) + dense bf16 MFMA GEMMs. Falls back to round-2 fused
// path if workspace is too small for the ~500 MB mean buffer.
// N=100000, E=700000, C1=128, C2=256, 7 edge types.

#define N_ET 7

typedef __bf16 bf16;
typedef __bf16 bf16x8 __attribute__((ext_vector_type(8)));
typedef __bf16 bf16x4 __attribute__((ext_vector_type(4)));
typedef __bf16 bf16x2 __attribute__((ext_vector_type(2)));
typedef float f32x4v __attribute__((ext_vector_type(4)));

// ---------------- CSR build ----------------

__global__ void count_edges_k(const int* __restrict__ row, const int* __restrict__ et,
                              int* __restrict__ cnt, int E) {
  int e = blockIdx.x * 256 + threadIdx.x;
  if (e < E) atomicAdd(&cnt[row[e] * N_ET + et[e]], 1);
}

__global__ void inv_counts_k(const int* __restrict__ cnt, float* __restrict__ inv, int n) {
  int i = blockIdx.x * 256 + threadIdx.x;
  if (i < n) inv[i] = 1.0f / fmaxf((float)cnt[i], 1.0f);
}

__global__ __launch_bounds__(1024) void scan1_k(const int* __restrict__ cnt,
                                                int* __restrict__ off,
                                                int* __restrict__ bsum, int n) {
  __shared__ int s[1024];
  int tid = threadIdx.x;
  int i = blockIdx.x * 1024 + tid;
  int v = (i < n) ? cnt[i] : 0;
  s[tid] = v;
  __syncthreads();
  for (int d = 1; d < 1024; d <<= 1) {
    int t = (tid >= d) ? s[tid - d] : 0;
    __syncthreads();
    s[tid] += t;
    __syncthreads();
  }
  if (i < n) off[i] = s[tid] - v;
  if (tid == 1023) bsum[blockIdx.x] = s[1023];
}

__global__ __launch_bounds__(1024) void scan2_k(int* __restrict__ bsum, int nb) {
  __shared__ int s[1024];
  int tid = threadIdx.x;
  int v = (tid < nb) ? bsum[tid] : 0;
  s[tid] = v;
  __syncthreads();
  for (int d = 1; d < 1024; d <<= 1) {
    int t = (tid >= d) ? s[tid - d] : 0;
    __syncthreads();
    s[tid] += t;
    __syncthreads();
  }
  if (tid < nb) bsum[tid] = s[tid] - v;
}

__global__ __launch_bounds__(1024) void scan3_k(int* __restrict__ off,
                                                const int* __restrict__ bsum,
                                                int n, int total) {
  int i = blockIdx.x * 1024 + threadIdx.x;
  if (i < n) off[i] += bsum[blockIdx.x];
  if (i == 0) off[n] = total;
}

__global__ void place_k(const int* __restrict__ row, const int* __restrict__ col,
                        const int* __restrict__ et, const int* __restrict__ off,
                        int* __restrict__ cur, int* __restrict__ pcol, int E) {
  int e = blockIdx.x * 256 + threadIdx.x;
  if (e >= E) return;
  int seg = row[e] * N_ET + et[e];
  int pos = off[seg] + atomicAdd(&cur[seg], 1);
  pcol[pos] = col[e];
}

// ---------------- weight transpose (f32 [K,256] -> bf16 [256,K]) ----------------

__global__ void transpose_w_k(const float* __restrict__ W, bf16* __restrict__ Bt, int K) {
  int i = blockIdx.x * 256 + threadIdx.x;
  if (i < K * 256) {
    int k = i >> 8, n = i & 255;
    Bt[(size_t)n * K + k] = (bf16)W[i];
  }
}

__global__ void cvt_bf16_k(const float* __restrict__ x, bf16* __restrict__ o, int n4) {
  int i = blockIdx.x * 256 + threadIdx.x;
  if (i >= n4) return;
  float4 v = *(const float4*)(x + (size_t)i * 4);
  bf16x4 r;
  r[0] = (bf16)v.x; r[1] = (bf16)v.y; r[2] = (bf16)v.z; r[3] = (bf16)v.w;
  *(bf16x4*)(o + (size_t)i * 4) = r;
}

// ---------------- dedicated aggregation (wave per segment) ----------------
// mean_a[m][t*128 + c] = inv[m*7+t] * sum_{p in seg} x[pcol[p]][c]   (ld = 896)
__global__ void agg_a_k(const float* __restrict__ x, const int* __restrict__ off,
                        const int* __restrict__ pcol, const float* __restrict__ inv,
                        bf16* __restrict__ mean, int NSg) {
  int wseg = (blockIdx.x * 256 + threadIdx.x) >> 6;
  if (wseg >= NSg) return;
  int lane = threadIdx.x & 63;
  int sS = off[wseg], sE = off[wseg + 1];
  float sc = inv[wseg];
  int m = wseg / N_ET, t = wseg - m * N_ET;
  float sx = 0.f, sy = 0.f;
  for (int p = sS; p < sE; ++p) {
    const float2 v = *(const float2*)(x + (size_t)pcol[p] * 128 + lane * 2);
    sx += v.x; sy += v.y;
  }
  bf16x2 o;
  o[0] = (bf16)(sx * sc);
  o[1] = (bf16)(sy * sc);
  *(bf16x2*)(mean + (size_t)m * 896 + t * 128 + lane * 2) = o;
}

// mean_b[m][t*256 + c] from bf16 x1[*,256]   (ld = 1792)
__global__ void agg_b_k(const bf16* __restrict__ x1, const int* __restrict__ off,
                        const int* __restrict__ pcol, const float* __restrict__ inv,
                        bf16* __restrict__ mean, int NSg) {
  int wseg = (blockIdx.x * 256 + threadIdx.x) >> 6;
  if (wseg >= NSg) return;
  int lane = threadIdx.x & 63;
  int sS = off[wseg], sE = off[wseg + 1];
  float sc = inv[wseg];
  int m = wseg / N_ET, t = wseg - m * N_ET;
  float s0 = 0.f, s1 = 0.f, s2 = 0.f, s3 = 0.f;
  for (int p = sS; p < sE; ++p) {
    bf16x4 v = *(const bf16x4*)(x1 + (size_t)pcol[p] * 256 + lane * 4);
    s0 += (float)v[0]; s1 += (float)v[1]; s2 += (float)v[2]; s3 += (float)v[3];
  }
  bf16x4 o;
  o[0] = (bf16)(s0 * sc); o[1] = (bf16)(s1 * sc);
  o[2] = (bf16)(s2 * sc); o[3] = (bf16)(s3 * sc);
  *(bf16x4*)(mean + (size_t)m * 1792 + t * 256 + lane * 4) = o;
}

// ---------------- dense bf16 GEMM: C[M,256] = A[M,K] @ Bt^T ----------------
// A bf16 row-major [Mpad,K] (Mpad >= grid*128, pad rows garbage-safe),
// Bt bf16 [256, K]. Tile 128x256, 4 waves (2x2: 64 rows x 128 cols), BK=32.
template <typename OT>
__launch_bounds__(256, 2)
__global__ void gemm_bf16_k(const bf16* __restrict__ A, const bf16* __restrict__ Bt,
                            OT* __restrict__ Cout, int M, int K) {
  __shared__ alignas(16) bf16 As[128][40];
  __shared__ alignas(16) bf16 Bs[256][40];
  const int t = threadIdx.x;
  const int m0 = blockIdx.x * 128;
  const int lane = t & 63, w = t >> 6;
  const int wm = (w >> 1) * 64;
  const int wn = (w & 1) * 128;
  const int l15 = lane & 15, quad = lane >> 4;

  f32x4v acc[4][8];
#pragma unroll
  for (int i = 0; i < 4; ++i)
#pragma unroll
    for (int j = 0; j < 8; ++j) acc[i][j] = (f32x4v){0.f, 0.f, 0.f, 0.f};

  const int r = t >> 1, h = t & 1;
  const bf16* arow = A + (size_t)(m0 + r) * K + h * 16;
  const bf16* brow = Bt + (size_t)t * K;

  for (int k0 = 0; k0 < K; k0 += 32) {
    bf16x8 a0 = *(const bf16x8*)(arow + k0);
    bf16x8 a1 = *(const bf16x8*)(arow + k0 + 8);
    bf16x8 b0 = *(const bf16x8*)(brow + k0 + 0);
    bf16x8 b1 = *(const bf16x8*)(brow + k0 + 8);
    bf16x8 b2 = *(const bf16x8*)(brow + k0 + 16);
    bf16x8 b3 = *(const bf16x8*)(brow + k0 + 24);
    *(bf16x8*)&As[r][h * 16] = a0;
    *(bf16x8*)&As[r][h * 16 + 8] = a1;
    *(bf16x8*)&Bs[t][0] = b0;
    *(bf16x8*)&Bs[t][8] = b1;
    *(bf16x8*)&Bs[t][16] = b2;
    *(bf16x8*)&Bs[t][24] = b3;
    __syncthreads();
    bf16x8 af[4], bfr[8];
#pragma unroll
    for (int f = 0; f < 4; ++f) af[f] = *(const bf16x8*)&As[wm + f * 16 + l15][quad * 8];
#pragma unroll
    for (int g = 0; g < 8; ++g) bfr[g] = *(const bf16x8*)&Bs[wn + g * 16 + l15][quad * 8];
#pragma unroll
    for (int fi = 0; fi < 4; ++fi)
#pragma unroll
      for (int fj = 0; fj < 8; ++fj)
        acc[fi][fj] = __builtin_amdgcn_mfma_f32_16x16x32_bf16(af[fi], bfr[fj], acc[fi][fj], 0, 0, 0);
    __syncthreads();
  }

#pragma unroll
  for (int fi = 0; fi < 4; ++fi) {
    int rbase = m0 + wm + fi * 16 + quad * 4;
#pragma unroll
    for (int rr = 0; rr < 4; ++rr) {
      int rowg = rbase + rr;
      if (rowg < M) {
#pragma unroll
        for (int fj = 0; fj < 8; ++fj)
          Cout[(size_t)rowg * 256 + wn + fj * 16 + l15] = (OT)acc[fi][fj][rr];
      }
    }
  }
}

// ---------------- round-2 fused kernel (fallback when ws is small) ----------------
template <int CF, bool AGG, typename XT, typename OT>
__launch_bounds__(256, 2)
__global__ void agg_gemm_k(const XT* __restrict__ X, const bf16* __restrict__ Bt,
                           const int* __restrict__ off, const int* __restrict__ pcol,
                           const float* __restrict__ inv, OT* __restrict__ Cout,
                           int M, int K) {
  __shared__ alignas(16) bf16 As[128][40];
  __shared__ alignas(16) bf16 Bs[256][40];
  const int t = threadIdx.x;
  const int m0 = blockIdx.x * 128;
  const int lane = t & 63, w = t >> 6;
  const int wm = (w >> 1) * 64;
  const int wn = (w & 1) * 128;
  const int l15 = lane & 15, quad = lane >> 4;

  f32x4v acc[4][8];
#pragma unroll
  for (int i = 0; i < 4; ++i)
#pragma unroll
    for (int j = 0; j < 8; ++j) acc[i][j] = (f32x4v){0.f, 0.f, 0.f, 0.f};

  const int r = t >> 1, h = t & 1;
  const int m = m0 + r;
  const bool mv = (m < M);

  for (int k0 = 0; k0 < K; k0 += 32) {
    if constexpr (AGG) {
      const int tt = k0 / CF;
      const int cb = (k0 % CF) + h * 16;
      int sS = 0, sE = 0;
      float sc = 0.f;
      if (mv) {
        int seg = m * N_ET + tt;
        sS = off[seg];
        sE = off[seg + 1];
        sc = inv[seg];
      }
      float s[16];
#pragma unroll
      for (int j = 0; j < 16; ++j) s[j] = 0.f;
      for (int p = sS; p < sE; ++p) {
        int cI = pcol[p];
        if constexpr (CF == 128) {
          const float* xp = (const float*)X + (size_t)cI * CF + cb;
          float4 v0 = *(const float4*)(xp + 0);
          float4 v1 = *(const float4*)(xp + 4);
          float4 v2 = *(const float4*)(xp + 8);
          float4 v3 = *(const float4*)(xp + 12);
          s[0] += v0.x; s[1] += v0.y; s[2] += v0.z; s[3] += v0.w;
          s[4] += v1.x; s[5] += v1.y; s[6] += v1.z; s[7] += v1.w;
          s[8] += v2.x; s[9] += v2.y; s[10] += v2.z; s[11] += v2.w;
          s[12] += v3.x; s[13] += v3.y; s[14] += v3.z; s[15] += v3.w;
        } else {
          const bf16* xp = (const bf16*)X + (size_t)cI * CF + cb;
          bf16x8 v0 = *(const bf16x8*)(xp);
          bf16x8 v1 = *(const bf16x8*)(xp + 8);
#pragma unroll
          for (int j = 0; j < 8; ++j) { s[j] += (float)v0[j]; s[8 + j] += (float)v1[j]; }
        }
      }
      bf16x8 o0, o1;
#pragma unroll
      for (int j = 0; j < 8; ++j) {
        o0[j] = (bf16)(s[j] * sc);
        o1[j] = (bf16)(s[8 + j] * sc);
      }
      *(bf16x8*)&As[r][h * 16] = o0;
      *(bf16x8*)&As[r][h * 16 + 8] = o1;
    } else {
      const float* xp = (const float*)X + (size_t)m * K + k0 + h * 16;
      float4 v0, v1, v2, v3;
      if (mv) {
        v0 = *(const float4*)(xp + 0);
        v1 = *(const float4*)(xp + 4);
        v2 = *(const float4*)(xp + 8);
        v3 = *(const float4*)(xp + 12);
      } else {
        v0 = v1 = v2 = v3 = make_float4(0.f, 0.f, 0.f, 0.f);
      }
      bf16x8 o0, o1;
      o0[0] = (bf16)v0.x; o0[1] = (bf16)v0.y; o0[2] = (bf16)v0.z; o0[3] = (bf16)v0.w;
      o0[4] = (bf16)v1.x; o0[5] = (bf16)v1.y; o0[6] = (bf16)v1.z; o0[7] = (bf16)v1.w;
      o1[0] = (bf16)v2.x; o1[1] = (bf16)v2.y; o1[2] = (bf16)v2.z; o1[3] = (bf16)v2.w;
      o1[4] = (bf16)v3.x; o1[5] = (bf16)v3.y; o1[6] = (bf16)v3.z; o1[7] = (bf16)v3.w;
      *(bf16x8*)&As[r][h * 16] = o0;
      *(bf16x8*)&As[r][h * 16 + 8] = o1;
    }
    {
      const bf16* bp = Bt + (size_t)t * K + k0;
      bf16x8 b0 = *(const bf16x8*)(bp + 0);
      bf16x8 b1 = *(const bf16x8*)(bp + 8);
      bf16x8 b2 = *(const bf16x8*)(bp + 16);
      bf16x8 b3 = *(const bf16x8*)(bp + 24);
      *(bf16x8*)&Bs[t][0] = b0;
      *(bf16x8*)&Bs[t][8] = b1;
      *(bf16x8*)&Bs[t][16] = b2;
      *(bf16x8*)&Bs[t][24] = b3;
    }
    __syncthreads();
    bf16x8 af[4], bfr[8];
#pragma unroll
    for (int f = 0; f < 4; ++f) af[f] = *(const bf16x8*)&As[wm + f * 16 + l15][quad * 8];
#pragma unroll
    for (int g = 0; g < 8; ++g) bfr[g] = *(const bf16x8*)&Bs[wn + g * 16 + l15][quad * 8];
#pragma unroll
    for (int fi = 0; fi < 4; ++fi)
#pragma unroll
      for (int fj = 0; fj < 8; ++fj)
        acc[fi][fj] = __builtin_amdgcn_mfma_f32_16x16x32_bf16(af[fi], bfr[fj], acc[fi][fj], 0, 0, 0);
    __syncthreads();
  }

#pragma unroll
  for (int fi = 0; fi < 4; ++fi) {
    int rbase = m0 + wm + fi * 16 + quad * 4;
#pragma unroll
    for (int rr = 0; rr < 4; ++rr) {
      int rowg = rbase + rr;
      if (rowg < M) {
#pragma unroll
        for (int fj = 0; fj < 8; ++fj)
          Cout[(size_t)rowg * 256 + wn + fj * 16 + l15] = (OT)acc[fi][fj][rr];
      }
    }
  }
}

// ---------------- BN stats / params / elementwise ----------------

__global__ void colstats_bf16_k(const bf16* __restrict__ v, int N,
                                float* __restrict__ s, float* __restrict__ q) {
  int c = threadIdx.x;
  float a = 0.f, b = 0.f;
  for (int r = blockIdx.x; r < N; r += gridDim.x) {
    float x = (float)v[(size_t)r * 256 + c];
    a += x;
    b += x * x;
  }
  unsafeAtomicAdd(&s[c], a);
  unsafeAtomicAdd(&q[c], b);
}

__global__ void colstats_f32_k(const float* __restrict__ v, int N,
                               float* __restrict__ s, float* __restrict__ q) {
  int c = threadIdx.x;
  float a = 0.f, b = 0.f;
  for (int r = blockIdx.x; r < N; r += gridDim.x) {
    float x = v[(size_t)r * 256 + c];
    a += x;
    b += x * x;
  }
  unsafeAtomicAdd(&s[c], a);
  unsafeAtomicAdd(&q[c], b);
}

__global__ void bn_params_k(const float* __restrict__ s, const float* __restrict__ q,
                            const float* __restrict__ g, const float* __restrict__ b,
                            float* __restrict__ scale, float* __restrict__ shift, float invN) {
  int c = threadIdx.x;
  float m = s[c] * invN;
  float var = fmaxf(q[c] * invN - m * m, 0.f);
  float sc = g[c] * rsqrtf(var + 1e-5f);
  scale[c] = sc;
  shift[c] = b[c] - m * sc;
}

__global__ void bn_relu_ip_k(bf16* __restrict__ v, const float* __restrict__ scale,
                             const float* __restrict__ shift, int total8) {
  int i = blockIdx.x * 256 + threadIdx.x;
  if (i >= total8) return;
  size_t base = (size_t)i * 8;
  int c = (int)(base & 255);
  bf16x8 x = *(const bf16x8*)(v + base);
#pragma unroll
  for (int j = 0; j < 8; ++j)
    x[j] = (bf16)fmaxf((float)x[j] * scale[c + j] + shift[c + j], 0.f);
  *(bf16x8*)(v + base) = x;
}

__global__ void final_out_k(const bf16* __restrict__ cb,
                            const float* __restrict__ scB, const float* __restrict__ shB,
                            const float* __restrict__ scS, const float* __restrict__ shS,
                            float* __restrict__ out, int total4) {
  int i = blockIdx.x * 256 + threadIdx.x;
  if (i >= total4) return;
  size_t base = (size_t)i * 4;
  int c = (int)(base & 255);
  bf16x4 vb = *(const bf16x4*)(cb + base);
  float4 vs = *(const float4*)(out + base);
  float4 r;
  r.x = fmaxf((float)vb[0] * scB[c + 0] + shB[c + 0] + vs.x * scS[c + 0] + shS[c + 0], 0.f);
  r.y = fmaxf((float)vb[1] * scB[c + 1] + shB[c + 1] + vs.y * scS[c + 1] + shS[c + 1], 0.f);
  r.z = fmaxf((float)vb[2] * scB[c + 2] + shB[c + 2] + vs.z * scS[c + 2] + shS[c + 2], 0.f);
  r.w = fmaxf((float)vb[3] * scB[c + 3] + shB[c + 3] + vs.w * scS[c + 3] + shS[c + 3], 0.f);
  *(float4*)(out + base) = r;
}

__global__ void sentinel_k(float* __restrict__ out, int n) {
  int i = blockIdx.x * 256 + threadIdx.x;
  if (i < n) out[i] = 12345.0f;
}

// ---------------- launch ----------------

extern "C" void kernel_launch(void* const* d_in, const int* in_sizes, int n_in,
                              void* d_out, int out_size, void* d_ws, size_t ws_size,
                              hipStream_t stream) {
  const float* x  = (const float*)d_in[0];
  const int* ei   = (const int*)d_in[1];
  const int* etp  = (const int*)d_in[2];
  const float* Wa = (const float*)d_in[4];
  const float* ga = (const float*)d_in[5];
  const float* ba = (const float*)d_in[6];
  const float* Wb = (const float*)d_in[7];
  const float* gb = (const float*)d_in[8];
  const float* bb = (const float*)d_in[9];
  const float* W1 = (const float*)d_in[10];
  const float* g1 = (const float*)d_in[11];
  const float* b1 = (const float*)d_in[12];

  const int C1 = 128, C2 = 256;
  const int N = in_sizes[0] / C1;   // 100000
  const int E = in_sizes[2];        // 700000
  const int* row = ei;
  const int* col = ei + E;
  const int NS = N * N_ET;
  const int KA = N_ET * C1;         // 896
  const int KB = N_ET * C2;         // 1792
  const int gemm_grid = (N + 127) / 128;       // 782
  const int Mpad = gemm_grid * 128;            // 100096

  const float invN = 1.0f / (float)N;
  const int nscan = (NS + 1023) / 1024;
  const int total8 = N * C2 / 8;
  const int total4 = N * C2 / 4;

  // ---- full-path workspace layout ----
  size_t need = 0;
  auto alloc = [&](size_t bytes) { size_t o = need; need += (bytes + 15) & ~(size_t)15; return o; };
  char* w = (char*)d_ws;
  int*   off_p = (int*)(w + alloc(((size_t)NS + 1) * 4));
  int*   cnt_p = (int*)(w + alloc((size_t)NS * 4));
  int*   pcol  = (int*)(w + alloc((size_t)E * 4));
  float* inv_p = (float*)(w + alloc((size_t)NS * 4));
  int*   bsum  = (int*)(w + alloc(1024 * 4));
  bf16*  BtA   = (bf16*)(w + alloc((size_t)256 * KA * 2));
  bf16*  BtB   = (bf16*)(w + alloc((size_t)256 * KB * 2));
  bf16*  Bt1   = (bf16*)(w + alloc((size_t)256 * C1 * 2));
  bf16*  x1    = (bf16*)(w + alloc((size_t)Mpad * C2 * 2));
  bf16*  convb = (bf16*)(w + alloc((size_t)N * C2 * 2));
  float* st    = (float*)(w + alloc(12 * 256 * 4));
  size_t need_base = need;
  bf16*  xb    = (bf16*)(w + alloc((size_t)Mpad * C1 * 2));
  bf16*  meanb = (bf16*)(w + alloc((size_t)Mpad * KB * 2));  // reused for mean_a (Mpad*KA)
  size_t need_full = need;

  if (ws_size < need_base) {
    sentinel_k<<<(out_size + 255) / 256, 256, 0, stream>>>((float*)d_out, out_size);
    return;
  }
  const bool full = (ws_size >= need_full);

  float* sum_a = st + 0 * 256, *ssq_a = st + 1 * 256;
  float* sum_b = st + 2 * 256, *ssq_b = st + 3 * 256;
  float* sum_s = st + 4 * 256, *ssq_s = st + 5 * 256;
  float* scA = st + 6 * 256, *shA = st + 7 * 256;
  float* scB = st + 8 * 256, *shB = st + 9 * 256;
  float* scS = st + 10 * 256, *shS = st + 11 * 256;

  // --- CSR build (both paths) ---
  hipMemsetAsync(cnt_p, 0, (size_t)NS * 4, stream);
  hipMemsetAsync(st, 0, 12 * 256 * 4, stream);
  count_edges_k<<<(E + 255) / 256, 256, 0, stream>>>(row, etp, cnt_p, E);
  inv_counts_k<<<(NS + 255) / 256, 256, 0, stream>>>(cnt_p, inv_p, NS);
  scan1_k<<<nscan, 1024, 0, stream>>>(cnt_p, off_p, bsum, NS);
  scan2_k<<<1, 1024, 0, stream>>>(bsum, nscan);
  scan3_k<<<nscan, 1024, 0, stream>>>(off_p, bsum, NS, E);
  hipMemsetAsync(cnt_p, 0, (size_t)NS * 4, stream);
  place_k<<<(E + 255) / 256, 256, 0, stream>>>(row, col, etp, off_p, cnt_p, pcol, E);

  // --- weight transposes ---
  transpose_w_k<<<(KA * 256 + 255) / 256, 256, 0, stream>>>(Wa, BtA, KA);
  transpose_w_k<<<(KB * 256 + 255) / 256, 256, 0, stream>>>(Wb, BtB, KB);
  transpose_w_k<<<(C1 * 256 + 255) / 256, 256, 0, stream>>>(W1, Bt1, C1);

  const int agg_grid = (NS + 3) / 4;  // wave per segment, 4 waves/block

  if (full) {
    // --- conv_a: aggregate -> mean_a (bf16 [Mpad,896]) -> GEMM -> x1buf ---
    agg_a_k<<<agg_grid, 256, 0, stream>>>(x, off_p, pcol, inv_p, meanb, NS);
    gemm_bf16_k<bf16><<<gemm_grid, 256, 0, stream>>>(meanb, BtA, x1, N, KA);
    colstats_bf16_k<<<512, 256, 0, stream>>>(x1, N, sum_a, ssq_a);
    bn_params_k<<<1, 256, 0, stream>>>(sum_a, ssq_a, ga, ba, scA, shA, invN);
    bn_relu_ip_k<<<(total8 + 255) / 256, 256, 0, stream>>>(x1, scA, shA, total8);

    // --- shortcut: xb = bf16(x); xb @ W1 -> d_out (f32) ---
    cvt_bf16_k<<<(N * C1 / 4 + 255) / 256, 256, 0, stream>>>(x, xb, N * C1 / 4);
    gemm_bf16_k<float><<<gemm_grid, 256, 0, stream>>>(xb, Bt1, (float*)d_out, N, C1);
    colstats_f32_k<<<512, 256, 0, stream>>>((const float*)d_out, N, sum_s, ssq_s);
    bn_params_k<<<1, 256, 0, stream>>>(sum_s, ssq_s, g1, b1, scS, shS, invN);

    // --- conv_b: aggregate x1 -> mean_b (bf16 [Mpad,1792]) -> GEMM -> convb ---
    agg_b_k<<<agg_grid, 256, 0, stream>>>(x1, off_p, pcol, inv_p, meanb, NS);
    gemm_bf16_k<bf16><<<gemm_grid, 256, 0, stream>>>(meanb, BtB, convb, N, KB);
    colstats_bf16_k<<<512, 256, 0, stream>>>(convb, N, sum_b, ssq_b);
    bn_params_k<<<1, 256, 0, stream>>>(sum_b, ssq_b, gb, bb, scB, shB, invN);
  } else {
    // --- round-2 fused fallback ---
    agg_gemm_k<128, true, float, bf16><<<gemm_grid, 256, 0, stream>>>(
        x, BtA, off_p, pcol, inv_p, x1, N, KA);
    colstats_bf16_k<<<512, 256, 0, stream>>>(x1, N, sum_a, ssq_a);
    bn_params_k<<<1, 256, 0, stream>>>(sum_a, ssq_a, ga, ba, scA, shA, invN);
    bn_relu_ip_k<<<(total8 + 255) / 256, 256, 0, stream>>>(x1, scA, shA, total8);

    agg_gemm_k<128, false, float, float><<<gemm_grid, 256, 0, stream>>>(
        x, Bt1, nullptr, nullptr, nullptr, (float*)d_out, N, C1);
    colstats_f32_k<<<512, 256, 0, stream>>>((const float*)d_out, N, sum_s, ssq_s);
    bn_params_k<<<1, 256, 0, stream>>>(sum_s, ssq_s, g1, b1, scS, shS, invN);

    agg_gemm_k<256, true, bf16, bf16><<<gemm_grid, 256, 0, stream>>>(
        x1, BtB, off_p, pcol, inv_p, convb, N, KB);
    colstats_bf16_k<<<512, 256, 0, stream>>>(convb, N, sum_b, ssq_b);
    bn_params_k<<<1, 256, 0, stream>>>(sum_b, ssq_b, gb, bb, scB, shB, invN);
  }

  // --- out = relu(bn(convb) + bn(scp)) ---
  final_out_k<<<(total4 + 255) / 256, 256, 0, stream>>>(
      convb, scB, shB, scS, shS, (float*)d_out, total4);
}

// Round 4
// 918.359 us; speedup vs baseline: 1.2962x; 1.2926x over previous
//
#include <hip/hip_runtime.h>
#include <cstdint>
#include <cstddef>

// GraphResBlock2 on MI355X — round 4: section-hoisted fused aggregate-GEMM.
// Aggregation done once per 128-wide K-section (per edge type) into a
// persistent LDS A-tile; B staged via pre-transposed 16B k-panels.
// Workspace ~115 MB (== proven round-2/3 envelope).
// N=100000, E=700000, C1=128, C2=256, 7 edge types.

#define N_ET 7

typedef __bf16 bf16;
typedef __bf16 bf16x8 __attribute__((ext_vector_type(8)));
typedef __bf16 bf16x4 __attribute__((ext_vector_type(4)));
typedef float f32x4v __attribute__((ext_vector_type(4)));

// ---------------- CSR build ----------------

__global__ void count_edges_k(const int* __restrict__ row, const int* __restrict__ et,
                              int* __restrict__ cnt, int E) {
  int e = blockIdx.x * 256 + threadIdx.x;
  if (e < E) atomicAdd(&cnt[row[e] * N_ET + et[e]], 1);
}

__global__ void inv_counts_k(const int* __restrict__ cnt, float* __restrict__ inv, int n) {
  int i = blockIdx.x * 256 + threadIdx.x;
  if (i < n) inv[i] = 1.0f / fmaxf((float)cnt[i], 1.0f);
}

__global__ __launch_bounds__(1024) void scan1_k(const int* __restrict__ cnt,
                                                int* __restrict__ off,
                                                int* __restrict__ bsum, int n) {
  __shared__ int s[1024];
  int tid = threadIdx.x;
  int i = blockIdx.x * 1024 + tid;
  int v = (i < n) ? cnt[i] : 0;
  s[tid] = v;
  __syncthreads();
  for (int d = 1; d < 1024; d <<= 1) {
    int t = (tid >= d) ? s[tid - d] : 0;
    __syncthreads();
    s[tid] += t;
    __syncthreads();
  }
  if (i < n) off[i] = s[tid] - v;
  if (tid == 1023) bsum[blockIdx.x] = s[1023];
}

__global__ __launch_bounds__(1024) void scan2_k(int* __restrict__ bsum, int nb) {
  __shared__ int s[1024];
  int tid = threadIdx.x;
  int v = (tid < nb) ? bsum[tid] : 0;
  s[tid] = v;
  __syncthreads();
  for (int d = 1; d < 1024; d <<= 1) {
    int t = (tid >= d) ? s[tid - d] : 0;
    __syncthreads();
    s[tid] += t;
    __syncthreads();
  }
  if (tid < nb) bsum[tid] = s[tid] - v;
}

__global__ __launch_bounds__(1024) void scan3_k(int* __restrict__ off,
                                                const int* __restrict__ bsum,
                                                int n, int total) {
  int i = blockIdx.x * 1024 + threadIdx.x;
  if (i < n) off[i] += bsum[blockIdx.x];
  if (i == 0) off[n] = total;
}

__global__ void place_k(const int* __restrict__ row, const int* __restrict__ col,
                        const int* __restrict__ et, const int* __restrict__ off,
                        int* __restrict__ cur, int* __restrict__ pcol, int E) {
  int e = blockIdx.x * 256 + threadIdx.x;
  if (e >= E) return;
  int seg = row[e] * N_ET + et[e];
  int pos = off[seg] + atomicAdd(&cur[seg], 1);
  pcol[pos] = col[e];
}

// ---------------- weight transposes ----------------
// panel layout for fused-v2: Bt8[k>>3][col][k&7]  (16B per (k-panel, col))
__global__ void transpose_w8_k(const float* __restrict__ W, bf16* __restrict__ Bt8, int K) {
  int i = blockIdx.x * 256 + threadIdx.x;
  if (i < K * 256) {
    int k = i >> 8, col = i & 255;
    Bt8[((size_t)(k >> 3) * 256 + col) * 8 + (k & 7)] = (bf16)W[i];
  }
}

// old layout for the shortcut kernel: Bt[col][k]
__global__ void transpose_w_k(const float* __restrict__ W, bf16* __restrict__ Bt, int K) {
  int i = blockIdx.x * 256 + threadIdx.x;
  if (i < K * 256) {
    int k = i >> 8, n = i & 255;
    Bt[(size_t)n * K + k] = (bf16)W[i];
  }
}

// ---------------- fused-v2: section-hoisted aggregate + GEMM ----------------
// Cout[M,256] (bf16) = Aeff[M, 7*CW] @ W, where
//   Aeff[m, type*CW + c] = inv[m*7+type] * sum_{p in seg(m,type)} X[pcol[p], c]
// Tile: 64 rows x 256 cols, 4 waves (2x2 -> 32 rows x 128 cols each).
// K processed in 128-wide sections; aggregation hoisted once per section.
// Thread (r = t>>2, h = t&3) aggregates 32 channels of row r.
template <int CW, typename XT>
__launch_bounds__(256, 3)
__global__ void agg_gemm2_k(const XT* __restrict__ X, const bf16* __restrict__ Bt8,
                            const int* __restrict__ off, const int* __restrict__ pcol,
                            const float* __restrict__ inv, bf16* __restrict__ Cout,
                            int M) {
  __shared__ alignas(16) bf16 As[64][136];          // 64 rows x 128-col section (+8 pad)
  __shared__ alignas(16) bf16 Bs[4][256][8];        // 4 k-panels x 256 cols x 8 k

  const int t = threadIdx.x;
  const int m0 = blockIdx.x * 64;
  const int lane = t & 63, w = t >> 6;
  const int wm = (w >> 1) * 32;
  const int wn = (w & 1) * 128;
  const int l15 = lane & 15, quad = lane >> 4;

  const int r = t >> 2, h = t & 3;                  // agg mapping
  const int m = m0 + r;
  const bool mv = (m < M);

  f32x4v acc[2][8];
#pragma unroll
  for (int i = 0; i < 2; ++i)
#pragma unroll
    for (int j = 0; j < 8; ++j) acc[i][j] = (f32x4v){0.f, 0.f, 0.f, 0.f};

  const int NSEC = (N_ET * CW) / 128;

  for (int sec = 0; sec < NSEC; ++sec) {
    // ---- aggregate this thread's (row, 32-channel) slice of the section ----
    const int type = (CW == 128) ? sec : (sec >> 1);
    const int xcol = ((sec * 128) & (CW - 1)) + h * 32;  // column base in X
    int sS = 0, sE = 0;
    float sc = 0.f;
    if (mv) {
      int seg = m * N_ET + type;
      sS = off[seg];
      sE = off[seg + 1];
      sc = inv[seg];
    }
    float s[32];
#pragma unroll
    for (int j = 0; j < 32; ++j) s[j] = 0.f;
    for (int p = sS; p < sE; ++p) {
      int cI = pcol[p];
      if constexpr (sizeof(XT) == 4) {
        const float* xp = (const float*)X + (size_t)cI * CW + xcol;
#pragma unroll
        for (int j = 0; j < 8; ++j) {
          float4 v = *(const float4*)(xp + j * 4);
          s[j * 4 + 0] += v.x; s[j * 4 + 1] += v.y;
          s[j * 4 + 2] += v.z; s[j * 4 + 3] += v.w;
        }
      } else {
        const bf16* xp = (const bf16*)X + (size_t)cI * CW + xcol;
#pragma unroll
        for (int j = 0; j < 4; ++j) {
          bf16x8 v = *(const bf16x8*)(xp + j * 8);
#pragma unroll
          for (int i = 0; i < 8; ++i) s[j * 8 + i] += (float)v[i];
        }
      }
    }
    __syncthreads();   // (b1) all waves done reading previous As
#pragma unroll
    for (int j = 0; j < 4; ++j) {
      bf16x8 o;
#pragma unroll
      for (int i = 0; i < 8; ++i) o[i] = (bf16)(s[j * 8 + i] * sc);
      *(bf16x8*)&As[r][h * 32 + j * 8] = o;
    }

    // ---- 4 k-iters over this section ----
#pragma unroll
    for (int kk = 0; kk < 4; ++kk) {
      const int k8b = sec * 16 + kk * 4;
      // stage B: wave w loads k-panel (k8b + w), 4 cols per thread, coalesced
      const bf16* gp = Bt8 + (size_t)(k8b + (t >> 6)) * 256 * 8;
      const int cb = t & 63;
      bf16x8 b0 = *(const bf16x8*)(gp + (cb + 0) * 8);
      bf16x8 b1 = *(const bf16x8*)(gp + (cb + 64) * 8);
      bf16x8 b2 = *(const bf16x8*)(gp + (cb + 128) * 8);
      bf16x8 b3 = *(const bf16x8*)(gp + (cb + 192) * 8);
      __syncthreads();   // (b2) prior frag reads done (and As visible on kk=0)
      *(bf16x8*)&Bs[t >> 6][cb + 0][0] = b0;
      *(bf16x8*)&Bs[t >> 6][cb + 64][0] = b1;
      *(bf16x8*)&Bs[t >> 6][cb + 128][0] = b2;
      *(bf16x8*)&Bs[t >> 6][cb + 192][0] = b3;
      __syncthreads();   // (b3) Bs visible

      bf16x8 af[2], bfr[8];
#pragma unroll
      for (int f = 0; f < 2; ++f)
        af[f] = *(const bf16x8*)&As[wm + f * 16 + l15][kk * 32 + quad * 8];
#pragma unroll
      for (int g = 0; g < 8; ++g)
        bfr[g] = *(const bf16x8*)&Bs[quad][wn + g * 16 + l15][0];
#pragma unroll
      for (int fi = 0; fi < 2; ++fi)
#pragma unroll
        for (int fj = 0; fj < 8; ++fj)
          acc[fi][fj] = __builtin_amdgcn_mfma_f32_16x16x32_bf16(af[fi], bfr[fj], acc[fi][fj], 0, 0, 0);
    }
  }

  // ---- epilogue: bf16 store ----
#pragma unroll
  for (int fi = 0; fi < 2; ++fi) {
    int rbase = m0 + wm + fi * 16 + quad * 4;
#pragma unroll
    for (int rr = 0; rr < 4; ++rr) {
      int rowg = rbase + rr;
      if (rowg < M) {
#pragma unroll
        for (int fj = 0; fj < 8; ++fj)
          Cout[(size_t)rowg * 256 + wn + fj * 16 + l15] = (bf16)acc[fi][fj][rr];
      }
    }
  }
}

// ---------------- shortcut dense GEMM (round-2 tested, AGG=false) ----------------
__launch_bounds__(256, 2)
__global__ void sc_gemm_k(const float* __restrict__ X, const bf16* __restrict__ Bt,
                          float* __restrict__ Cout, int M, int K) {
  __shared__ alignas(16) bf16 As[128][40];
  __shared__ alignas(16) bf16 Bs[256][40];
  const int t = threadIdx.x;
  const int m0 = blockIdx.x * 128;
  const int lane = t & 63, w = t >> 6;
  const int wm = (w >> 1) * 64;
  const int wn = (w & 1) * 128;
  const int l15 = lane & 15, quad = lane >> 4;

  f32x4v acc[4][8];
#pragma unroll
  for (int i = 0; i < 4; ++i)
#pragma unroll
    for (int j = 0; j < 8; ++j) acc[i][j] = (f32x4v){0.f, 0.f, 0.f, 0.f};

  const int r = t >> 1, h = t & 1;
  const int m = m0 + r;
  const bool mv = (m < M);

  for (int k0 = 0; k0 < K; k0 += 32) {
    const float* xp = X + (size_t)m * K + k0 + h * 16;
    float4 v0, v1, v2, v3;
    if (mv) {
      v0 = *(const float4*)(xp + 0);
      v1 = *(const float4*)(xp + 4);
      v2 = *(const float4*)(xp + 8);
      v3 = *(const float4*)(xp + 12);
    } else {
      v0 = v1 = v2 = v3 = make_float4(0.f, 0.f, 0.f, 0.f);
    }
    bf16x8 o0, o1;
    o0[0] = (bf16)v0.x; o0[1] = (bf16)v0.y; o0[2] = (bf16)v0.z; o0[3] = (bf16)v0.w;
    o0[4] = (bf16)v1.x; o0[5] = (bf16)v1.y; o0[6] = (bf16)v1.z; o0[7] = (bf16)v1.w;
    o1[0] = (bf16)v2.x; o1[1] = (bf16)v2.y; o1[2] = (bf16)v2.z; o1[3] = (bf16)v2.w;
    o1[4] = (bf16)v3.x; o1[5] = (bf16)v3.y; o1[6] = (bf16)v3.z; o1[7] = (bf16)v3.w;
    *(bf16x8*)&As[r][h * 16] = o0;
    *(bf16x8*)&As[r][h * 16 + 8] = o1;
    {
      const bf16* bp = Bt + (size_t)t * K + k0;
      bf16x8 b0 = *(const bf16x8*)(bp + 0);
      bf16x8 b1 = *(const bf16x8*)(bp + 8);
      bf16x8 b2 = *(const bf16x8*)(bp + 16);
      bf16x8 b3 = *(const bf16x8*)(bp + 24);
      *(bf16x8*)&Bs[t][0] = b0;
      *(bf16x8*)&Bs[t][8] = b1;
      *(bf16x8*)&Bs[t][16] = b2;
      *(bf16x8*)&Bs[t][24] = b3;
    }
    __syncthreads();
    bf16x8 af[4], bfr[8];
#pragma unroll
    for (int f = 0; f < 4; ++f) af[f] = *(const bf16x8*)&As[wm + f * 16 + l15][quad * 8];
#pragma unroll
    for (int g = 0; g < 8; ++g) bfr[g] = *(const bf16x8*)&Bs[wn + g * 16 + l15][quad * 8];
#pragma unroll
    for (int fi = 0; fi < 4; ++fi)
#pragma unroll
      for (int fj = 0; fj < 8; ++fj)
        acc[fi][fj] = __builtin_amdgcn_mfma_f32_16x16x32_bf16(af[fi], bfr[fj], acc[fi][fj], 0, 0, 0);
    __syncthreads();
  }

#pragma unroll
  for (int fi = 0; fi < 4; ++fi) {
    int rbase = m0 + wm + fi * 16 + quad * 4;
#pragma unroll
    for (int rr = 0; rr < 4; ++rr) {
      int rowg = rbase + rr;
      if (rowg < M) {
#pragma unroll
        for (int fj = 0; fj < 8; ++fj)
          Cout[(size_t)rowg * 256 + wn + fj * 16 + l15] = acc[fi][fj][rr];
      }
    }
  }
}

// ---------------- BN stats / params / elementwise ----------------

__global__ void colstats_bf16_k(const bf16* __restrict__ v, int N,
                                float* __restrict__ s, float* __restrict__ q) {
  int c = threadIdx.x;
  float a = 0.f, b = 0.f;
  for (int r = blockIdx.x; r < N; r += gridDim.x) {
    float x = (float)v[(size_t)r * 256 + c];
    a += x;
    b += x * x;
  }
  unsafeAtomicAdd(&s[c], a);
  unsafeAtomicAdd(&q[c], b);
}

__global__ void colstats_f32_k(const float* __restrict__ v, int N,
                               float* __restrict__ s, float* __restrict__ q) {
  int c = threadIdx.x;
  float a = 0.f, b = 0.f;
  for (int r = blockIdx.x; r < N; r += gridDim.x) {
    float x = v[(size_t)r * 256 + c];
    a += x;
    b += x * x;
  }
  unsafeAtomicAdd(&s[c], a);
  unsafeAtomicAdd(&q[c], b);
}

__global__ void bn_params_k(const float* __restrict__ s, const float* __restrict__ q,
                            const float* __restrict__ g, const float* __restrict__ b,
                            float* __restrict__ scale, float* __restrict__ shift, float invN) {
  int c = threadIdx.x;
  float m = s[c] * invN;
  float var = fmaxf(q[c] * invN - m * m, 0.f);
  float sc = g[c] * rsqrtf(var + 1e-5f);
  scale[c] = sc;
  shift[c] = b[c] - m * sc;
}

__global__ void bn_relu_ip_k(bf16* __restrict__ v, const float* __restrict__ scale,
                             const float* __restrict__ shift, int total8) {
  int i = blockIdx.x * 256 + threadIdx.x;
  if (i >= total8) return;
  size_t base = (size_t)i * 8;
  int c = (int)(base & 255);
  bf16x8 x = *(const bf16x8*)(v + base);
#pragma unroll
  for (int j = 0; j < 8; ++j)
    x[j] = (bf16)fmaxf((float)x[j] * scale[c + j] + shift[c + j], 0.f);
  *(bf16x8*)(v + base) = x;
}

__global__ void final_out_k(const bf16* __restrict__ cb,
                            const float* __restrict__ scB, const float* __restrict__ shB,
                            const float* __restrict__ scS, const float* __restrict__ shS,
                            float* __restrict__ out, int total4) {
  int i = blockIdx.x * 256 + threadIdx.x;
  if (i >= total4) return;
  size_t base = (size_t)i * 4;
  int c = (int)(base & 255);
  bf16x4 vb = *(const bf16x4*)(cb + base);
  float4 vs = *(const float4*)(out + base);
  float4 r;
  r.x = fmaxf((float)vb[0] * scB[c + 0] + shB[c + 0] + vs.x * scS[c + 0] + shS[c + 0], 0.f);
  r.y = fmaxf((float)vb[1] * scB[c + 1] + shB[c + 1] + vs.y * scS[c + 1] + shS[c + 1], 0.f);
  r.z = fmaxf((float)vb[2] * scB[c + 2] + shB[c + 2] + vs.z * scS[c + 2] + shS[c + 2], 0.f);
  r.w = fmaxf((float)vb[3] * scB[c + 3] + shB[c + 3] + vs.w * scS[c + 3] + shS[c + 3], 0.f);
  *(float4*)(out + base) = r;
}

__global__ void sentinel_k(float* __restrict__ out, int n) {
  int i = blockIdx.x * 256 + threadIdx.x;
  if (i < n) out[i] = 12345.0f;
}

// ---------------- launch ----------------

extern "C" void kernel_launch(void* const* d_in, const int* in_sizes, int n_in,
                              void* d_out, int out_size, void* d_ws, size_t ws_size,
                              hipStream_t stream) {
  const float* x  = (const float*)d_in[0];
  const int* ei   = (const int*)d_in[1];
  const int* etp  = (const int*)d_in[2];
  const float* Wa = (const float*)d_in[4];
  const float* ga = (const float*)d_in[5];
  const float* ba = (const float*)d_in[6];
  const float* Wb = (const float*)d_in[7];
  const float* gb = (const float*)d_in[8];
  const float* bb = (const float*)d_in[9];
  const float* W1 = (const float*)d_in[10];
  const float* g1 = (const float*)d_in[11];
  const float* b1 = (const float*)d_in[12];

  const int C1 = 128, C2 = 256;
  const int N = in_sizes[0] / C1;   // 100000
  const int E = in_sizes[2];        // 700000
  const int* row = ei;
  const int* col = ei + E;
  const int NS = N * N_ET;
  const int KA = N_ET * C1;         // 896
  const int KB = N_ET * C2;         // 1792

  size_t need = 0;
  auto alloc = [&](size_t bytes) { size_t o = need; need += (bytes + 15) & ~(size_t)15; return o; };
  char* w = (char*)d_ws;
  int*   off_p = (int*)(w + alloc(((size_t)NS + 1) * 4));
  int*   cnt_p = (int*)(w + alloc((size_t)NS * 4));
  int*   pcol  = (int*)(w + alloc((size_t)E * 4));
  float* inv_p = (float*)(w + alloc((size_t)NS * 4));
  int*   bsum  = (int*)(w + alloc(1024 * 4));
  bf16*  Bt8A  = (bf16*)(w + alloc((size_t)KA * 256 * 2));
  bf16*  Bt8B  = (bf16*)(w + alloc((size_t)KB * 256 * 2));
  bf16*  Bt1   = (bf16*)(w + alloc((size_t)256 * C1 * 2));
  bf16*  x1    = (bf16*)(w + alloc((size_t)N * C2 * 2));
  bf16*  convb = (bf16*)(w + alloc((size_t)N * C2 * 2));
  float* st    = (float*)(w + alloc(12 * 256 * 4));

  if (ws_size < need) {
    sentinel_k<<<(out_size + 255) / 256, 256, 0, stream>>>((float*)d_out, out_size);
    return;
  }

  float* sum_a = st + 0 * 256, *ssq_a = st + 1 * 256;
  float* sum_b = st + 2 * 256, *ssq_b = st + 3 * 256;
  float* sum_s = st + 4 * 256, *ssq_s = st + 5 * 256;
  float* scA = st + 6 * 256, *shA = st + 7 * 256;
  float* scB = st + 8 * 256, *shB = st + 9 * 256;
  float* scS = st + 10 * 256, *shS = st + 11 * 256;

  const float invN = 1.0f / (float)N;
  const int nscan = (NS + 1023) / 1024;
  const int g2 = (N + 63) / 64;          // fused-v2 grid (64-row tiles)
  const int gsc = (N + 127) / 128;       // shortcut grid
  const int total8 = N * C2 / 8;
  const int total4 = N * C2 / 4;

  // --- CSR build ---
  hipMemsetAsync(cnt_p, 0, (size_t)NS * 4, stream);
  hipMemsetAsync(st, 0, 12 * 256 * 4, stream);
  count_edges_k<<<(E + 255) / 256, 256, 0, stream>>>(row, etp, cnt_p, E);
  inv_counts_k<<<(NS + 255) / 256, 256, 0, stream>>>(cnt_p, inv_p, NS);
  scan1_k<<<nscan, 1024, 0, stream>>>(cnt_p, off_p, bsum, NS);
  scan2_k<<<1, 1024, 0, stream>>>(bsum, nscan);
  scan3_k<<<nscan, 1024, 0, stream>>>(off_p, bsum, NS, E);
  hipMemsetAsync(cnt_p, 0, (size_t)NS * 4, stream);
  place_k<<<(E + 255) / 256, 256, 0, stream>>>(row, col, etp, off_p, cnt_p, pcol, E);

  // --- weight transposes ---
  transpose_w8_k<<<(KA * 256 + 255) / 256, 256, 0, stream>>>(Wa, Bt8A, KA);
  transpose_w8_k<<<(KB * 256 + 255) / 256, 256, 0, stream>>>(Wb, Bt8B, KB);
  transpose_w_k<<<(C1 * 256 + 255) / 256, 256, 0, stream>>>(W1, Bt1, C1);

  // --- conv_a: fused-v2 -> x1 (pre-BN bf16), then BN+ReLU in place ---
  agg_gemm2_k<128, float><<<g2, 256, 0, stream>>>(x, Bt8A, off_p, pcol, inv_p, x1, N);
  colstats_bf16_k<<<512, 256, 0, stream>>>(x1, N, sum_a, ssq_a);
  bn_params_k<<<1, 256, 0, stream>>>(sum_a, ssq_a, ga, ba, scA, shA, invN);
  bn_relu_ip_k<<<(total8 + 255) / 256, 256, 0, stream>>>(x1, scA, shA, total8);

  // --- shortcut: x @ W1 -> d_out (f32) ---
  sc_gemm_k<<<gsc, 256, 0, stream>>>(x, Bt1, (float*)d_out, N, C1);
  colstats_f32_k<<<512, 256, 0, stream>>>((const float*)d_out, N, sum_s, ssq_s);
  bn_params_k<<<1, 256, 0, stream>>>(sum_s, ssq_s, g1, b1, scS, shS, invN);

  // --- conv_b: fused-v2 from x1 -> convb (pre-BN bf16) ---
  agg_gemm2_k<256, bf16><<<g2, 256, 0, stream>>>(x1, Bt8B, off_p, pcol, inv_p, convb, N);
  colstats_bf16_k<<<512, 256, 0, stream>>>(convb, N, sum_b, ssq_b);
  bn_params_k<<<1, 256, 0, stream>>>(sum_b, ssq_b, gb, bb, scB, shB, invN);

  // --- out = relu(bn(convb) + bn(scp)) ---
  final_out_k<<<(total4 + 255) / 256, 256, 0, stream>>>(
      convb, scB, shB, scS, shS, (float*)d_out, total4);
}